// Round 13
// baseline (465.251 us; speedup 1.0000x reference)
//
#include <hip/hip_runtime.h>
#include <math.h>

#define NB    256   // blocks; 4 batch rows each; 2 blocks/CU (independent barrier domains)
#define NT    256   // 4 waves: 0-1 layer0 (X), 2-3 layer1 (Y); each wave covers 2 unit-groups
#define ROWS  4
#define B_TOT 1024
#define T_TOT 512
#define HROW  104   // f16 per h-row (208 B stride; 16B-aligned)
#define XT    32

typedef _Float16 f16;
typedef _Float16 f16x8 __attribute__((ext_vector_type(8)));
typedef float    f32x4 __attribute__((ext_vector_type(4)));

__device__ __forceinline__ float rcp_f(float v){ return __builtin_amdgcn_rcpf(v); }
__device__ __forceinline__ float sig_f(float x){ return rcp_f(1.0f + __expf(-x)); }
__device__ __forceinline__ float tanh_f(float x){ return 1.0f - 2.0f*rcp_f(__expf(2.0f*x) + 1.0f); }

#define MFMA16(a,b,c) __builtin_amdgcn_mfma_f32_16x16x32_f16((a),(b),(c),0,0,0)

__global__ __launch_bounds__(NT, 2) void lstm_pipe2(
    const float* __restrict__ x,
    const float* __restrict__ h0i, const float* __restrict__ c0i,
    const float* __restrict__ wih0, const float* __restrict__ whh0,
    const float* __restrict__ bih0, const float* __restrict__ bhh0,
    const float* __restrict__ wih1, const float* __restrict__ whh1,
    const float* __restrict__ bih1, const float* __restrict__ bhh1,
    const float* __restrict__ wmean, const float* __restrict__ bmean,
    const float* __restrict__ wcrit, const float* __restrict__ bcrit,
    float* __restrict__ out)
{
    const int tid  = threadIdx.x;
    const int lane = tid & 63;
    const int wv   = tid >> 6;        // 0..3
    const bool isX = (wv < 2);
    const int wq   = wv & 1;          // covers unit-groups {2wq, 2wq+1}
    const int l15  = lane & 15;       // A row (gate-unit) / B col (batch)
    const int kgrp = lane >> 4;
    const int r0   = blockIdx.x * ROWS;
    const int uloc = lane >> 2;       // owned unit-local 0..15 (cell phase)
    const int bb   = lane & 3;        // owned batch row

    __shared__ __align__(16) f16 hbuf[2][16][HROW];   // rows 0-3 batch; cols 64-68 x
    __shared__ __align__(16) f16 ybuf[2][16][HROW];
    __shared__ float xt[ROWS][XT][5];
    // [wave][ugroup-slot][gate][batch][unit-local]
    __shared__ __align__(16) float gbuf[4][2][4][ROWS][16];

    // ---- A-fragments: 2 unit-groups per wave ----
    f16x8 afr[2][4][4];   // [sg][gate][chunk]; X: chunks 0,1 whh0 + 2 (x|0) + 3 zero; Y: 0,1 wih1; 2,3 whh1
    float bpk[2][4];
    float cOwn[2];

    if (isX){
#pragma unroll
        for (int sg = 0; sg < 2; ++sg){
            const int ug = 2*wq + sg;
#pragma unroll
            for (int q = 0; q < 4; ++q){
                const int gr = q*64 + ug*16 + l15;
#pragma unroll
                for (int c2 = 0; c2 < 2; ++c2){
                    const float* pw = whh0 + (size_t)gr*64 + c2*32 + kgrp*8;
                    f16x8 v;
#pragma unroll
                    for (int j = 0; j < 8; ++j) v[j] = (f16)pw[j];
                    afr[sg][q][c2] = v;
                }
                {   // chunk 2: k 64..95 -> x-weight cols 0..4, rest 0
                    f16x8 v;
#pragma unroll
                    for (int j = 0; j < 8; ++j){
                        int k = kgrp*8 + j;
                        v[j] = (k < 5) ? (f16)wih0[gr*5 + k] : (f16)0.f;
                    }
                    afr[sg][q][2] = v;
                }
                afr[sg][q][3] = (f16x8)(f16)0.f;
                const int gu = q*64 + ug*16 + uloc;
                bpk[sg][q] = bih0[gu] + bhh0[gu];
            }
            cOwn[sg] = c0i[(size_t)(r0 + bb)*64 + ug*16 + uloc];
        }
    } else {
#pragma unroll
        for (int sg = 0; sg < 2; ++sg){
            const int ug = 2*wq + sg;
#pragma unroll
            for (int q = 0; q < 4; ++q){
                const int gr = q*64 + ug*16 + l15;
#pragma unroll
                for (int c2 = 0; c2 < 2; ++c2){
                    const float* pw = wih1 + (size_t)gr*64 + c2*32 + kgrp*8;
                    const float* qw = whh1 + (size_t)gr*64 + c2*32 + kgrp*8;
                    f16x8 v, u2;
#pragma unroll
                    for (int j = 0; j < 8; ++j){ v[j] = (f16)pw[j]; u2[j] = (f16)qw[j]; }
                    afr[sg][q][c2]   = v;
                    afr[sg][q][2+c2] = u2;
                }
                const int gu = q*64 + ug*16 + uloc;
                bpk[sg][q] = bih1[gu] + bhh1[gu];
            }
            cOwn[sg] = c0i[(size_t)B_TOT*64 + (size_t)(r0 + bb)*64 + ug*16 + uloc];
        }
    }

    // ---- LDS init ----
    for (int e = tid; e < 2*16*HROW; e += NT){
        ((f16*)hbuf)[e] = (f16)0.f;
        ((f16*)ybuf)[e] = (f16)0.f;
    }
    __syncthreads();
    if (tid < ROWS*64){
        int cc = tid >> 6, u = tid & 63;
        hbuf[0][cc][u] = (f16)h0i[(size_t)(r0+cc)*64 + u];
        ybuf[1][cc][u] = (f16)h0i[(size_t)B_TOT*64 + (size_t)(r0+cc)*64 + u];
    }
    if (tid < ROWS*5){
        int cc = tid/5, i = tid - cc*5;
        hbuf[0][cc][64+i] = (f16)x[(size_t)(r0+cc)*T_TOT*5 + i];  // x[0]
    }
    for (int e = tid; e < ROWS*XT*5; e += NT){
        int r = e/(XT*5), rem = e - r*(XT*5), ts = rem/5, i = rem - ts*5;
        xt[r][ts][i] = x[((size_t)(r0+r)*T_TOT + ts)*5 + i];      // tile 0
    }
    __syncthreads();

    // ---- 513 pipelined ticks: X = layer0 step t, Y = layer1 step t-1 ----
#pragma unroll 1
    for (int t = 0; t <= T_TOT; ++t){
        const int p = t & 1;

        if ((t+1) < T_TOT && ((t+1) & 31) == 0){      // stage next x tile
            for (int e = tid; e < ROWS*XT*5; e += NT){
                int r = e/(XT*5), rem = e - r*(XT*5), ts = rem/5, i = rem - ts*5;
                xt[r][ts][i] = x[((size_t)(r0+r)*T_TOT + (t+1+ts))*5 + i];
            }
            __syncthreads();
        }
        if ((t+1) < T_TOT && tid < ROWS*5){           // x[t+1] -> write-side buffer
            int cc = tid/5, i = tid - cc*5;
            hbuf[p^1][cc][64+i] = (f16)xt[cc][(t+1)&31][i];
        }

        if (isX){ if (t < T_TOT){
            __builtin_amdgcn_s_setprio(1);
            const f16* bp = &hbuf[p][l15][kgrp*8];
            f16x8 b0 = *(const f16x8*)(bp);
            f16x8 b1 = *(const f16x8*)(bp + 32);
            f16x8 b2 = *(const f16x8*)(bp + 64);
#pragma unroll
            for (int sg = 0; sg < 2; ++sg){
#pragma unroll
                for (int q = 0; q < 4; ++q){
                    f32x4 a = {0.f,0.f,0.f,0.f};
                    a = MFMA16(afr[sg][q][0], b0, a);
                    a = MFMA16(afr[sg][q][1], b1, a);
                    a = MFMA16(afr[sg][q][2], b2, a);
                    if (l15 < ROWS) *(f32x4*)&gbuf[wv][sg][q][l15][kgrp*4] = a;
                }
                float gi = gbuf[wv][sg][0][bb][uloc] + bpk[sg][0];
                float gf = gbuf[wv][sg][1][bb][uloc] + bpk[sg][1];
                float gg = gbuf[wv][sg][2][bb][uloc] + bpk[sg][2];
                float go = gbuf[wv][sg][3][bb][uloc] + bpk[sg][3];
                cOwn[sg] = sig_f(gf)*cOwn[sg] + sig_f(gi)*tanh_f(gg);
                hbuf[p^1][bb][(2*wq+sg)*16 + uloc] = (f16)(sig_f(go)*tanh_f(cOwn[sg]));
            }
            __builtin_amdgcn_s_setprio(0);
        }} else { if (t >= 1){
            __builtin_amdgcn_s_setprio(1);
            const f16* hp = &hbuf[p][l15][kgrp*8];
            f16x8 b0 = *(const f16x8*)(hp);
            f16x8 b1 = *(const f16x8*)(hp + 32);
            const f16* yp = &ybuf[p][l15][kgrp*8];
            f16x8 y0 = *(const f16x8*)(yp);
            f16x8 y1 = *(const f16x8*)(yp + 32);
#pragma unroll
            for (int sg = 0; sg < 2; ++sg){
#pragma unroll
                for (int q = 0; q < 4; ++q){
                    f32x4 a = {0.f,0.f,0.f,0.f};
                    a = MFMA16(afr[sg][q][0], b0, a);
                    a = MFMA16(afr[sg][q][1], b1, a);
                    a = MFMA16(afr[sg][q][2], y0, a);
                    a = MFMA16(afr[sg][q][3], y1, a);
                    if (l15 < ROWS) *(f32x4*)&gbuf[wv][sg][q][l15][kgrp*4] = a;
                }
                float gi = gbuf[wv][sg][0][bb][uloc] + bpk[sg][0];
                float gf = gbuf[wv][sg][1][bb][uloc] + bpk[sg][1];
                float gg = gbuf[wv][sg][2][bb][uloc] + bpk[sg][2];
                float go = gbuf[wv][sg][3][bb][uloc] + bpk[sg][3];
                cOwn[sg] = sig_f(gf)*cOwn[sg] + sig_f(gi)*tanh_f(gg);
                ybuf[p^1][bb][(2*wq+sg)*16 + uloc] = (f16)(sig_f(go)*tanh_f(cOwn[sg]));
            }
            __builtin_amdgcn_s_setprio(0);
        }}
        __syncthreads();
    }

    // ---- heads: final h1 = ybuf[1] (tick 512, p=0, wrote p^1=1) ----
    if (wv < ROWS){
        const int cc = wv, u = lane;
        float hr = (float)ybuf[1][cc][u];
        float pm = hr * wmean[u];
        float pc = hr * wcrit[u];
#pragma unroll
        for (int o = 32; o > 0; o >>= 1){
            pm += __shfl_down(pm, o);
            pc += __shfl_down(pc, o);
        }
        if (u == 0){
            float m = pm + bmean[0];
            out[r0+cc]           = 2.f*tanh_f(m);
            out[B_TOT + r0+cc]   = __logf(1.f + __expf(m));
            out[2*B_TOT + r0+cc] = pc + bcrit[0];
        }
    }
}

extern "C" void kernel_launch(void* const* d_in, const int* in_sizes, int n_in,
                              void* d_out, int out_size, void* d_ws, size_t ws_size,
                              hipStream_t stream) {
    const float* x     = (const float*)d_in[0];
    const float* h0i   = (const float*)d_in[1];
    const float* c0i   = (const float*)d_in[2];
    const float* wih0  = (const float*)d_in[3];
    const float* whh0  = (const float*)d_in[4];
    const float* bih0  = (const float*)d_in[5];
    const float* bhh0  = (const float*)d_in[6];
    const float* wih1  = (const float*)d_in[7];
    const float* whh1  = (const float*)d_in[8];
    const float* bih1  = (const float*)d_in[9];
    const float* bhh1  = (const float*)d_in[10];
    const float* wmean = (const float*)d_in[11];
    const float* bmean = (const float*)d_in[12];
    const float* wcrit = (const float*)d_in[13];
    const float* bcrit = (const float*)d_in[14];

    lstm_pipe2<<<NB, NT, 0, stream>>>(x, h0i, c0i, wih0, whh0, bih0, bhh0,
                                      wih1, whh1, bih1, bhh1,
                                      wmean, bmean, wcrit, bcrit,
                                      (float*)d_out);
}

// Round 15
// 355.391 us; speedup vs baseline: 1.3091x; 1.3091x over previous
//
#include <hip/hip_runtime.h>
#include <math.h>

#define NB    256   // blocks = CU count; 4 batch rows each
#define NT    512   // 8 waves: 0-3 layer0 (X), 4-7 layer1 (Y)
#define ROWS  4
#define B_TOT 1024
#define T_TOT 512
#define HROW  104   // f16 per h-row (208 B stride; 16B-aligned)
#define XT    32

typedef _Float16 f16;
typedef _Float16 f16x8 __attribute__((ext_vector_type(8)));
typedef float    f32x4 __attribute__((ext_vector_type(4)));

__device__ __forceinline__ float rcp_f(float v){ return __builtin_amdgcn_rcpf(v); }
__device__ __forceinline__ float sig_f(float x){ return rcp_f(1.0f + __expf(-x)); }
__device__ __forceinline__ float tanh_f(float x){ return 1.0f - 2.0f*rcp_f(__expf(2.0f*x) + 1.0f); }

// DPP row_shr:N within each 16-lane row: dst lane i reads src lane i-N
// (data moves toward HIGHER lanes; R14 used row_shl = wrong direction)
template<int CTRL>
__device__ __forceinline__ float dpp_mov(float v){
    int r = __builtin_amdgcn_update_dpp(0, __float_as_int(v), CTRL, 0xF, 0xF, false);
    return __int_as_float(r);
}

#define MFMA16(a,b,c) __builtin_amdgcn_mfma_f32_16x16x32_f16((a),(b),(c),0,0,0)

__global__ __launch_bounds__(NT, 2) void lstm_dpp(
    const float* __restrict__ x,
    const float* __restrict__ h0i, const float* __restrict__ c0i,
    const float* __restrict__ wih0, const float* __restrict__ whh0,
    const float* __restrict__ bih0, const float* __restrict__ bhh0,
    const float* __restrict__ wih1, const float* __restrict__ whh1,
    const float* __restrict__ bih1, const float* __restrict__ bhh1,
    const float* __restrict__ wmean, const float* __restrict__ bmean,
    const float* __restrict__ wcrit, const float* __restrict__ bcrit,
    float* __restrict__ out)
{
    const int tid  = threadIdx.x;
    const int lane = tid & 63;
    const int wv   = tid >> 6;
    const bool isX = (wv < 4);
    const int w    = wv & 3;          // unit-group: units [16w, 16w+16)
    const int l15  = lane & 15;       // A-row m / B-col (batch)
    const int kgrp = lane >> 4;
    const int r0   = blockIdx.x * ROWS;
    // A-row decomposition: m = usub*4 + gate
    const int gA   = l15 & 3;         // gate of this lane's A-row
    const int usA  = l15 >> 2;        // unit-sub of A-row
    // owned cell after DPP spread: lane l15 = 4*grp + bown
    const int grp  = l15 >> 2;        // tile index owned
    const int bown = l15 & 3;         // batch row owned
    const int uown = 16*w + 4*grp + kgrp;   // unit owned

    __shared__ __align__(16) f16 hbuf[2][16][HROW];   // rows 0-3 batch; cols 64-68 x
    __shared__ __align__(16) f16 ybuf[2][16][HROW];
    __shared__ float xt[ROWS][XT][5];

    // ---- A-fragments (weights) + bias acc-init ----
    f16x8 afr[4][4];   // [tile s][k-chunk]; X: 0,1 whh0 + 2 (x|0) + 3 zero; Y: 0,1 wih1; 2,3 whh1
    f32x4 bv[4];       // bv[s][r] = bias[gate r][unit 16w+4s+kgrp]
    float cOwn;

    if (isX){
#pragma unroll
        for (int s = 0; s < 4; ++s){
            const int gr = gA*64 + 16*w + 4*s + usA;   // weight row for A-row l15, tile s
#pragma unroll
            for (int c2 = 0; c2 < 2; ++c2){
                const float* pw = whh0 + (size_t)gr*64 + c2*32 + kgrp*8;
                f16x8 v;
#pragma unroll
                for (int j = 0; j < 8; ++j) v[j] = (f16)pw[j];
                afr[s][c2] = v;
            }
            {   // chunk 2: global k 64..95 -> x-weight cols 0..4, rest 0
                f16x8 v;
#pragma unroll
                for (int j = 0; j < 8; ++j){
                    int k = kgrp*8 + j;
                    v[j] = (k < 5) ? (f16)wih0[gr*5 + k] : (f16)0.f;
                }
                afr[s][2] = v;
            }
            afr[s][3] = (f16x8)(f16)0.f;
            const int us = 16*w + 4*s + kgrp;
            f32x4 bb;
#pragma unroll
            for (int r = 0; r < 4; ++r) bb[r] = bih0[r*64 + us] + bhh0[r*64 + us];
            bv[s] = bb;
        }
        cOwn = c0i[(size_t)(r0 + bown)*64 + uown];
    } else {
#pragma unroll
        for (int s = 0; s < 4; ++s){
            const int gr = gA*64 + 16*w + 4*s + usA;
#pragma unroll
            for (int c2 = 0; c2 < 2; ++c2){
                const float* pw = wih1 + (size_t)gr*64 + c2*32 + kgrp*8;
                const float* qw = whh1 + (size_t)gr*64 + c2*32 + kgrp*8;
                f16x8 v, u2;
#pragma unroll
                for (int j = 0; j < 8; ++j){ v[j] = (f16)pw[j]; u2[j] = (f16)qw[j]; }
                afr[s][c2]   = v;
                afr[s][2+c2] = u2;
            }
            const int us = 16*w + 4*s + kgrp;
            f32x4 bb;
#pragma unroll
            for (int r = 0; r < 4; ++r) bb[r] = bih1[r*64 + us] + bhh1[r*64 + us];
            bv[s] = bb;
        }
        cOwn = c0i[(size_t)B_TOT*64 + (size_t)(r0 + bown)*64 + uown];
    }

    // ---- LDS init ----
    for (int e = tid; e < 2*16*HROW; e += NT){
        ((f16*)hbuf)[e] = (f16)0.f;
        ((f16*)ybuf)[e] = (f16)0.f;
    }
    __syncthreads();
    if (tid < ROWS*64){
        int cc = tid >> 6, u = tid & 63;
        hbuf[0][cc][u] = (f16)h0i[(size_t)(r0+cc)*64 + u];
        ybuf[1][cc][u] = (f16)h0i[(size_t)B_TOT*64 + (size_t)(r0+cc)*64 + u];
    }
    if (tid < ROWS*5){
        int cc = tid/5, i = tid - cc*5;
        hbuf[0][cc][64+i] = (f16)x[(size_t)(r0+cc)*T_TOT*5 + i];  // x[0]
    }
    for (int e = tid; e < ROWS*XT*5; e += NT){
        int r = e/(XT*5), rem = e - r*(XT*5), ts = rem/5, i = rem - ts*5;
        xt[r][ts][i] = x[((size_t)(r0+r)*T_TOT + ts)*5 + i];      // tile 0
    }
    __syncthreads();

    // ---- 513 pipelined ticks: X = layer0 step t, Y = layer1 step t-1 ----
#pragma unroll 1
    for (int t = 0; t <= T_TOT; ++t){
        const int p = t & 1;

        if ((t+1) < T_TOT && ((t+1) & 31) == 0){      // stage next x tile
            for (int e = tid; e < ROWS*XT*5; e += NT){
                int r = e/(XT*5), rem = e - r*(XT*5), ts = rem/5, i = rem - ts*5;
                xt[r][ts][i] = x[((size_t)(r0+r)*T_TOT + (t+1+ts))*5 + i];
            }
            __syncthreads();
        }
        if ((t+1) < T_TOT && tid < ROWS*5){           // x[t+1] -> write-side buffer
            int cc = tid/5, i = tid - cc*5;
            hbuf[p^1][cc][64+i] = (f16)xt[cc][(t+1)&31][i];
        }

        if (isX){ if (t < T_TOT){
            __builtin_amdgcn_s_setprio(1);
            const f16* bp = &hbuf[p][l15][kgrp*8];
            f16x8 b0 = *(const f16x8*)(bp);
            f16x8 b1 = *(const f16x8*)(bp + 32);
            f16x8 b2 = *(const f16x8*)(bp + 64);
            f32x4 a0 = bv[0], a1 = bv[1], a2 = bv[2], a3 = bv[3];
            a0 = MFMA16(afr[0][0], b0, a0); a0 = MFMA16(afr[0][1], b1, a0); a0 = MFMA16(afr[0][2], b2, a0);
            a1 = MFMA16(afr[1][0], b0, a1); a1 = MFMA16(afr[1][1], b1, a1); a1 = MFMA16(afr[1][2], b2, a1);
            a2 = MFMA16(afr[2][0], b0, a2); a2 = MFMA16(afr[2][1], b1, a2); a2 = MFMA16(afr[2][2], b2, a2);
            a3 = MFMA16(afr[3][0], b0, a3); a3 = MFMA16(afr[3][1], b1, a3); a3 = MFMA16(afr[3][2], b2, a3);
            // spread: tile s -> dest lanes l15 = 4s+b via row_shr:4s (dst i reads i-4s)
            float g0, g1, g2, g3;
            {
                float s10 = dpp_mov<0x114>(a1[0]), s20 = dpp_mov<0x118>(a2[0]), s30 = dpp_mov<0x11C>(a3[0]);
                float s11 = dpp_mov<0x114>(a1[1]), s21 = dpp_mov<0x118>(a2[1]), s31 = dpp_mov<0x11C>(a3[1]);
                float s12 = dpp_mov<0x114>(a1[2]), s22 = dpp_mov<0x118>(a2[2]), s32 = dpp_mov<0x11C>(a3[2]);
                float s13 = dpp_mov<0x114>(a1[3]), s23 = dpp_mov<0x118>(a2[3]), s33 = dpp_mov<0x11C>(a3[3]);
                g0 = (grp==0)?a0[0]:(grp==1)?s10:(grp==2)?s20:s30;
                g1 = (grp==0)?a0[1]:(grp==1)?s11:(grp==2)?s21:s31;
                g2 = (grp==0)?a0[2]:(grp==1)?s12:(grp==2)?s22:s32;
                g3 = (grp==0)?a0[3]:(grp==1)?s13:(grp==2)?s23:s33;
            }
            // cell update (reg r = gate r): i,f,g,o
            cOwn = sig_f(g1)*cOwn + sig_f(g0)*tanh_f(g2);
            hbuf[p^1][bown][uown] = (f16)(sig_f(g3)*tanh_f(cOwn));
            __builtin_amdgcn_s_setprio(0);
        }} else { if (t >= 1){
            __builtin_amdgcn_s_setprio(1);
            const f16* hp = &hbuf[p][l15][kgrp*8];
            f16x8 b0 = *(const f16x8*)(hp);
            f16x8 b1 = *(const f16x8*)(hp + 32);
            const f16* yp = &ybuf[p][l15][kgrp*8];
            f16x8 y0 = *(const f16x8*)(yp);
            f16x8 y1 = *(const f16x8*)(yp + 32);
            f32x4 a0 = bv[0], a1 = bv[1], a2 = bv[2], a3 = bv[3];
            a0 = MFMA16(afr[0][0], b0, a0); a0 = MFMA16(afr[0][1], b1, a0);
            a0 = MFMA16(afr[0][2], y0, a0); a0 = MFMA16(afr[0][3], y1, a0);
            a1 = MFMA16(afr[1][0], b0, a1); a1 = MFMA16(afr[1][1], b1, a1);
            a1 = MFMA16(afr[1][2], y0, a1); a1 = MFMA16(afr[1][3], y1, a1);
            a2 = MFMA16(afr[2][0], b0, a2); a2 = MFMA16(afr[2][1], b1, a2);
            a2 = MFMA16(afr[2][2], y0, a2); a2 = MFMA16(afr[2][3], y1, a2);
            a3 = MFMA16(afr[3][0], b0, a3); a3 = MFMA16(afr[3][1], b1, a3);
            a3 = MFMA16(afr[3][2], y0, a3); a3 = MFMA16(afr[3][3], y1, a3);
            float g0, g1, g2, g3;
            {
                float s10 = dpp_mov<0x114>(a1[0]), s20 = dpp_mov<0x118>(a2[0]), s30 = dpp_mov<0x11C>(a3[0]);
                float s11 = dpp_mov<0x114>(a1[1]), s21 = dpp_mov<0x118>(a2[1]), s31 = dpp_mov<0x11C>(a3[1]);
                float s12 = dpp_mov<0x114>(a1[2]), s22 = dpp_mov<0x118>(a2[2]), s32 = dpp_mov<0x11C>(a3[2]);
                float s13 = dpp_mov<0x114>(a1[3]), s23 = dpp_mov<0x118>(a2[3]), s33 = dpp_mov<0x11C>(a3[3]);
                g0 = (grp==0)?a0[0]:(grp==1)?s10:(grp==2)?s20:s30;
                g1 = (grp==0)?a0[1]:(grp==1)?s11:(grp==2)?s21:s31;
                g2 = (grp==0)?a0[2]:(grp==1)?s12:(grp==2)?s22:s32;
                g3 = (grp==0)?a0[3]:(grp==1)?s13:(grp==2)?s23:s33;
            }
            cOwn = sig_f(g1)*cOwn + sig_f(g0)*tanh_f(g2);
            ybuf[p^1][bown][uown] = (f16)(sig_f(g3)*tanh_f(cOwn));
            __builtin_amdgcn_s_setprio(0);
        }}
        __syncthreads();
    }

    // ---- heads: final h1 = ybuf[1] (tick 512, p=0, wrote p^1=1) ----
    if (wv < ROWS){
        const int cc = wv, u = lane;
        float hr = (float)ybuf[1][cc][u];
        float pm = hr * wmean[u];
        float pc = hr * wcrit[u];
#pragma unroll
        for (int o = 32; o > 0; o >>= 1){
            pm += __shfl_down(pm, o);
            pc += __shfl_down(pc, o);
        }
        if (u == 0){
            float m = pm + bmean[0];
            out[r0+cc]           = 2.f*tanh_f(m);
            out[B_TOT + r0+cc]   = __logf(1.f + __expf(m));
            out[2*B_TOT + r0+cc] = pc + bcrit[0];
        }
    }
}

extern "C" void kernel_launch(void* const* d_in, const int* in_sizes, int n_in,
                              void* d_out, int out_size, void* d_ws, size_t ws_size,
                              hipStream_t stream) {
    const float* x     = (const float*)d_in[0];
    const float* h0i   = (const float*)d_in[1];
    const float* c0i   = (const float*)d_in[2];
    const float* wih0  = (const float*)d_in[3];
    const float* whh0  = (const float*)d_in[4];
    const float* bih0  = (const float*)d_in[5];
    const float* bhh0  = (const float*)d_in[6];
    const float* wih1  = (const float*)d_in[7];
    const float* whh1  = (const float*)d_in[8];
    const float* bih1  = (const float*)d_in[9];
    const float* bhh1  = (const float*)d_in[10];
    const float* wmean = (const float*)d_in[11];
    const float* bmean = (const float*)d_in[12];
    const float* wcrit = (const float*)d_in[13];
    const float* bcrit = (const float*)d_in[14];

    lstm_dpp<<<NB, NT, 0, stream>>>(x, h0i, c0i, wih0, whh0, bih0, bhh0,
                                    wih1, whh1, bih1, bhh1,
                                    wmean, bmean, wcrit, bcrit,
                                    (float*)d_out);
}